// Round 1
// baseline (267.278 us; speedup 1.0000x reference)
//
#include <hip/hip_runtime.h>
#include <math.h>

#define BT 1024
#define BN 1024
#define D  256
#define H  8
#define DH 32
#define TB 8   // target rows per attention block

// ---------------------------------------------------------------------------
// ek/ev: ek[t,:] = E[t,:] @ Wk^T   (no bias; bias lives in K0/V0)
// 1 block, 256 threads; thread j computes ek[0..1][j], ev[0..1][j]
// ---------------------------------------------------------------------------
__global__ __launch_bounds__(256) void ekev_kernel(
    const float* __restrict__ E, const float* __restrict__ Wk,
    const float* __restrict__ Wv, float* __restrict__ ek, float* __restrict__ ev) {
  int j = threadIdx.x;
  const float* wk = Wk + j * D;
  const float* wv = Wv + j * D;
  for (int t = 0; t < 2; ++t) {
    const float* e = E + t * D;
    float ak = 0.f, av = 0.f;
    for (int k = 0; k < D; k += 4) {
      float4 e4 = *(const float4*)(e + k);
      float4 k4 = *(const float4*)(wk + k);
      float4 v4 = *(const float4*)(wv + k);
      ak += e4.x * k4.x + e4.y * k4.y + e4.z * k4.z + e4.w * k4.w;
      av += e4.x * v4.x + e4.y * v4.y + e4.z * v4.z + e4.w * v4.w;
    }
    ek[t * D + j] = ak;
    ev[t * D + j] = av;
  }
}

// ---------------------------------------------------------------------------
// Generic row-major Y = X @ W^T + b for [N,256] x [256,256].
// 4 rows per block, 256 cols (one col per thread). X staged in LDS.
// ---------------------------------------------------------------------------
__device__ __forceinline__ void proj_body(
    const float* __restrict__ X, const float* __restrict__ W,
    const float* __restrict__ bias, float* __restrict__ Y, int r0) {
  __shared__ float4 xs[4][D / 4];
  {
    int rr = threadIdx.x >> 6;   // 0..3
    int kk = threadIdx.x & 63;   // float4 index 0..63
    xs[rr][kk] = *(const float4*)(X + (size_t)(r0 + rr) * D + kk * 4);
  }
  __syncthreads();
  int col = threadIdx.x;
  const float* w = W + (size_t)col * D;
  float acc0 = 0.f, acc1 = 0.f, acc2 = 0.f, acc3 = 0.f;
#pragma unroll 8
  for (int k4 = 0; k4 < D / 4; ++k4) {
    float4 w4 = *(const float4*)(w + k4 * 4);
    float4 x0 = xs[0][k4];
    float4 x1 = xs[1][k4];
    float4 x2 = xs[2][k4];
    float4 x3 = xs[3][k4];
    acc0 += x0.x * w4.x + x0.y * w4.y + x0.z * w4.z + x0.w * w4.w;
    acc1 += x1.x * w4.x + x1.y * w4.y + x1.z * w4.z + x1.w * w4.w;
    acc2 += x2.x * w4.x + x2.y * w4.y + x2.z * w4.z + x2.w * w4.w;
    ac3_dummy:
    acc3 += x3.x * w4.x + x3.y * w4.y + x3.z * w4.z + x3.w * w4.w;
  }
  float b = bias[col];
  Y[(size_t)(r0 + 0) * D + col] = acc0 + b;
  Y[(size_t)(r0 + 1) * D + col] = acc1 + b;
  Y[(size_t)(r0 + 2) * D + col] = acc2 + b;
  Y[(size_t)(r0 + 3) * D + col] = acc3 + b;
}

// Fused Q / K0 / V0 projections. grid = (BT/4, 3).
__global__ __launch_bounds__(256) void qkv_kernel(
    const float* __restrict__ ht, const float* __restrict__ hn,
    const float* __restrict__ Wq, const float* __restrict__ bq,
    const float* __restrict__ Wk, const float* __restrict__ bk,
    const float* __restrict__ Wv, const float* __restrict__ bv,
    float* __restrict__ Q, float* __restrict__ K0, float* __restrict__ V0) {
  const float *X, *W, *b;
  float* Y;
  switch (blockIdx.y) {
    case 0:  X = ht; W = Wq; b = bq; Y = Q;  break;
    case 1:  X = hn; W = Wk; b = bk; Y = K0; break;
    default: X = hn; W = Wv; b = bv; Y = V0; break;
  }
  proj_body(X, W, b, Y, blockIdx.x * 4);
}

// Output projection: out = O @ Wo^T + bo. grid = BT/4.
__global__ __launch_bounds__(256) void proj_out_kernel(
    const float* __restrict__ O, const float* __restrict__ Wo,
    const float* __restrict__ bo, float* __restrict__ out) {
  proj_body(O, Wo, bo, out, blockIdx.x * 4);
}

// ---------------------------------------------------------------------------
// Attention: block = (TB=8 target rows) x (1 head), 256 threads.
// thread tid -> r = tid>>5 (row in tile), j = tid&31 (lane within row group).
// Phase 1: scores into LDS (with mask/et tags).  Phase 2: softmax + s0/s1.
// Phase 3: out[r, h*32 + j] = attn @ V0 + s1*ev1 + s0*ev0.
// ---------------------------------------------------------------------------
__global__ __launch_bounds__(256) void attn_kernel(
    const float* __restrict__ Q, const float* __restrict__ K0,
    const float* __restrict__ V0, const float* __restrict__ ekp,
    const float* __restrict__ evp, const int* __restrict__ adj,
    const int* __restrict__ ety, float* __restrict__ O) {
  __shared__ float sc[TB][BN];          // scores -> attn weights
  __shared__ unsigned char tg[TB][BN];  // 255 = masked, else edge type 0/1
  __shared__ float s0s[TB], s1s[TB];

  const int h   = blockIdx.y;
  const int b0  = blockIdx.x * TB;
  const int tid = threadIdx.x;
  const int r   = tid >> 5;
  const int j   = tid & 31;
  const int row = b0 + r;

  // q row-head slice in registers (identical across the 32 threads of a row)
  float q[DH];
  {
    const float* qp = Q + (size_t)row * D + h * DH;
#pragma unroll
    for (int d = 0; d < DH; d += 4) {
      float4 t4 = *(const float4*)(qp + d);
      q[d] = t4.x; q[d + 1] = t4.y; q[d + 2] = t4.z; q[d + 3] = t4.w;
    }
  }
  // qe[t] = q . ek[t, head slice]
  float qe0 = 0.f, qe1 = 0.f;
  {
    const float* e0 = ekp + h * DH;
    const float* e1 = ekp + D + h * DH;
#pragma unroll
    for (int d = 0; d < DH; ++d) {
      qe0 += q[d] * e0[d];
      qe1 += q[d] * e1[d];
    }
  }
  const float scale = 0.17677669529663687f;  // 1/sqrt(32)

  // ---- Phase 1: scores ----
  const int* arow = adj + (size_t)row * BN;
  const int* trow = ety + (size_t)row * BN;
#pragma unroll 4
  for (int i = 0; i < BN / 32; ++i) {
    int n = j + 32 * i;
    int a = arow[n];
    int t = trow[n];
    float s = -1e30f;
    unsigned char tag = 255;
    if (a != 0) {
      const float* kp = K0 + (size_t)n * D + h * DH;
      float dot = 0.f;
#pragma unroll
      for (int d = 0; d < DH; d += 4) {
        float4 k4 = *(const float4*)(kp + d);
        dot += q[d] * k4.x + q[d + 1] * k4.y + q[d + 2] * k4.z + q[d + 3] * k4.w;
      }
      s = (dot + (t ? qe1 : qe0)) * scale;
      tag = (unsigned char)t;
    }
    sc[r][n] = s;
    tg[r][n] = tag;
  }
  __syncthreads();

  // ---- Phase 2: softmax per row (32 threads per row) ----
  float m = -3.4e38f;
  for (int i = 0; i < BN / 32; ++i) m = fmaxf(m, sc[r][j + 32 * i]);
#pragma unroll
  for (int off = 16; off >= 1; off >>= 1) m = fmaxf(m, __shfl_xor(m, off, 32));

  float e_loc[BN / 32];
  float denom = 0.f, s1 = 0.f;
  for (int i = 0; i < BN / 32; ++i) {
    int n = j + 32 * i;
    unsigned char tag = tg[r][n];
    float e = (tag == 255) ? 0.f : __expf(sc[r][n] - m);
    e_loc[i] = e;
    denom += e;
    if (tag == 1) s1 += e;
  }
#pragma unroll
  for (int off = 16; off >= 1; off >>= 1) {
    denom += __shfl_xor(denom, off, 32);
    s1    += __shfl_xor(s1, off, 32);
  }
  float inv = denom > 0.f ? 1.f / denom : 0.f;
  for (int i = 0; i < BN / 32; ++i) sc[r][j + 32 * i] = e_loc[i] * inv;
  if (j == 0) {
    s1s[r] = s1 * inv;
    s0s[r] = (denom - s1) * inv;
  }
  __syncthreads();

  // ---- Phase 3: out = attn @ V0 + s1*ev1 + s0*ev0 ----
  {
    int d = j;
    const float* vp = V0 + h * DH + d;
    float acc = 0.f;
    for (int n = 0; n < BN; n += 4) {
      float4 a4 = *(const float4*)&sc[r][n];
      acc += a4.x * vp[(size_t)(n + 0) * D] + a4.y * vp[(size_t)(n + 1) * D] +
             a4.z * vp[(size_t)(n + 2) * D] + a4.w * vp[(size_t)(n + 3) * D];
    }
    float o = acc + s1s[r] * evp[D + h * DH + d] + s0s[r] * evp[h * DH + d];
    O[(size_t)row * D + h * DH + d] = o;
  }
}

// ---------------------------------------------------------------------------
extern "C" void kernel_launch(void* const* d_in, const int* in_sizes, int n_in,
                              void* d_out, int out_size, void* d_ws, size_t ws_size,
                              hipStream_t stream) {
  const float* h_target = (const float*)d_in[0];
  const float* h_neigh  = (const float*)d_in[1];
  const int*   adjacency= (const int*)d_in[2];
  const int*   edge_ty  = (const int*)d_in[3];
  const float* Wq = (const float*)d_in[4];
  const float* bq = (const float*)d_in[5];
  const float* Wk = (const float*)d_in[6];
  const float* bk = (const float*)d_in[7];
  const float* Wv = (const float*)d_in[8];
  const float* bv = (const float*)d_in[9];
  const float* Wo = (const float*)d_in[10];
  const float* bo = (const float*)d_in[11];
  const float* E  = (const float*)d_in[12];
  float* out = (float*)d_out;

  float* ws = (float*)d_ws;
  float* Q  = ws;                 // BT*D
  float* K0 = Q  + (size_t)BT * D; // BN*D
  float* V0 = K0 + (size_t)BN * D; // BN*D
  float* O  = V0 + (size_t)BN * D; // BT*D
  float* ek = O  + (size_t)BT * D; // 2*D
  float* ev = ek + 2 * D;          // 2*D

  ekev_kernel<<<1, 256, 0, stream>>>(E, Wk, Wv, ek, ev);
  qkv_kernel<<<dim3(BT / 4, 3), 256, 0, stream>>>(h_target, h_neigh, Wq, bq, Wk,
                                                  bk, Wv, bv, Q, K0, V0);
  attn_kernel<<<dim3(BT / TB, H), 256, 0, stream>>>(Q, K0, V0, ek, ev,
                                                    adjacency, edge_ty, O);
  proj_out_kernel<<<BT / 4, 256, 0, stream>>>(O, Wo, bo, out);
}

// Round 2
// 190.438 us; speedup vs baseline: 1.4035x; 1.4035x over previous
//
#include <hip/hip_runtime.h>
#include <math.h>

#define BT 1024
#define BN 1024
#define D  256
#define H  8
#define DH 32

// ===========================================================================
// ekev: ek[t,:] = E[t,:] @ Wk^T ; ev[t,:] = E[t,:] @ Wv^T  (no bias)
// grid (8,2): x = 32-col group, y = {k,v}. thread = (c=32, kseg=8).
// ===========================================================================
__global__ __launch_bounds__(256) void ekev_kernel(
    const float* __restrict__ E, const float* __restrict__ Wk,
    const float* __restrict__ Wv, float* __restrict__ ek, float* __restrict__ ev) {
  const int tid = threadIdx.x;
  const int c = tid >> 3, kseg = tid & 7;
  const int col = blockIdx.x * 32 + c;
  const float* W = blockIdx.y ? Wv : Wk;
  float* outp = blockIdx.y ? ev : ek;
  const float* wrow = W + (size_t)col * D + kseg * 32;
  const float* e0p = E + kseg * 32;
  const float* e1p = E + D + kseg * 32;
  float p0 = 0.f, p1 = 0.f;
#pragma unroll
  for (int i = 0; i < 8; ++i) {
    float4 w4 = *(const float4*)(wrow + i * 4);
    float4 a4 = *(const float4*)(e0p + i * 4);
    float4 b4 = *(const float4*)(e1p + i * 4);
    p0 += w4.x * a4.x + w4.y * a4.y + w4.z * a4.z + w4.w * a4.w;
    p1 += w4.x * b4.x + w4.y * b4.y + w4.z * b4.z + w4.w * b4.w;
  }
#pragma unroll
  for (int off = 1; off <= 4; off <<= 1) {
    p0 += __shfl_xor(p0, off);
    p1 += __shfl_xor(p1, off);
  }
  if (kseg == 0) {
    outp[col] = p0;
    outp[D + col] = p1;
  }
}

// ===========================================================================
// Projection Y = X @ W^T + b, 4 rows x 256 cols per block, k-tiles of 32.
// W-tile staged in LDS [256][36] (pad breaks bank alignment), X transposed
// [k][8] for broadcast float4 reads. thread = output col.
// ===========================================================================
__device__ __forceinline__ void proj_body(
    const float* __restrict__ X, const float* __restrict__ W,
    const float* __restrict__ bias, float* __restrict__ Y, int r0) {
  __shared__ float wlds[256][36];  // [col][k within tile], stride 36 floats
  __shared__ float xlds[32][8];    // [k][row], rows 0..3 used

  const int tid = threadIdx.x;
  float acc0 = 0.f, acc1 = 0.f, acc2 = 0.f, acc3 = 0.f;

  for (int kt = 0; kt < 8; ++kt) {
    const int k0 = kt * 32;
    // stage W: 256 cols x 32 k = 2048 float4 / 256 threads = 8 each
#pragma unroll
    for (int j = 0; j < 8; ++j) {
      int idx = j * 256 + tid;
      int col = idx >> 3;
      int kc = idx & 7;
      float4 w4 = *(const float4*)(W + (size_t)col * D + k0 + kc * 4);
      *(float4*)&wlds[col][kc * 4] = w4;
    }
    // stage X transposed: 4 rows x 32 k
    if (tid < 128) {
      int kk = tid & 31, r = tid >> 5;
      xlds[kk][r] = X[(size_t)(r0 + r) * D + k0 + kk];
    }
    __syncthreads();
#pragma unroll
    for (int kc = 0; kc < 8; ++kc) {
      float4 w4 = *(const float4*)&wlds[tid][kc * 4];
      float4 xa = *(const float4*)&xlds[kc * 4 + 0][0];
      float4 xb = *(const float4*)&xlds[kc * 4 + 1][0];
      float4 xc = *(const float4*)&xlds[kc * 4 + 2][0];
      float4 xd = *(const float4*)&xlds[kc * 4 + 3][0];
      acc0 = fmaf(w4.x, xa.x, acc0); acc1 = fmaf(w4.x, xa.y, acc1);
      acc2 = fmaf(w4.x, xa.z, acc2); acc3 = fmaf(w4.x, xa.w, acc3);
      acc0 = fmaf(w4.y, xb.x, acc0); acc1 = fmaf(w4.y, xb.y, acc1);
      acc2 = fmaf(w4.y, xb.z, acc2); acc3 = fmaf(w4.y, xb.w, acc3);
      acc0 = fmaf(w4.z, xc.x, acc0); acc1 = fmaf(w4.z, xc.y, acc1);
      acc2 = fmaf(w4.z, xc.z, acc2); acc3 = fmaf(w4.z, xc.w, acc3);
      acc0 = fmaf(w4.w, xd.x, acc0); acc1 = fmaf(w4.w, xd.y, acc1);
      acc2 = fmaf(w4.w, xd.z, acc2); acc3 = fmaf(w4.w, xd.w, acc3);
    }
    __syncthreads();
  }
  const float b = bias[tid];
  Y[(size_t)(r0 + 0) * D + tid] = acc0 + b;
  Y[(size_t)(r0 + 1) * D + tid] = acc1 + b;
  Y[(size_t)(r0 + 2) * D + tid] = acc2 + b;
  Y[(size_t)(r0 + 3) * D + tid] = acc3 + b;
}

__global__ __launch_bounds__(256) void qkv_kernel(
    const float* __restrict__ ht, const float* __restrict__ hn,
    const float* __restrict__ Wq, const float* __restrict__ bq,
    const float* __restrict__ Wk, const float* __restrict__ bk,
    const float* __restrict__ Wv, const float* __restrict__ bv,
    float* __restrict__ Q, float* __restrict__ K0, float* __restrict__ V0) {
  const float *X, *W, *b;
  float* Y;
  switch (blockIdx.y) {
    case 0:  X = ht; W = Wq; b = bq; Y = Q;  break;
    case 1:  X = hn; W = Wk; b = bk; Y = K0; break;
    default: X = hn; W = Wv; b = bv; Y = V0; break;
  }
  proj_body(X, W, b, Y, blockIdx.x * 4);
}

__global__ __launch_bounds__(256) void proj_out_kernel(
    const float* __restrict__ O, const float* __restrict__ Wo,
    const float* __restrict__ bo, float* __restrict__ out) {
  proj_body(O, Wo, bo, out, blockIdx.x * 4);
}

// ===========================================================================
// Attention, one-pass (no max subtraction; |scores| <~ 12 so exp is safe).
// Block: 4 target rows x 4 heads (head group hg = blockIdx.y). 256 threads.
// n-tiles of 64. Per tile:
//   stage: K-tile -> LDS [64][132] (coalesced), tags -> LDS, V -> regs
//   A: thread=(h=4, n_sub=64): e = exp((q.k + qe)*scale) -> LDS; local denom/s1
//   B: thread=(h=4, d4=8, n_oct=8): acc[r] += e * V (e broadcast from LDS)
// End: wave-reduce denom/s1 (A layout), octet-reduce acc (B layout), write O.
// ===========================================================================
#define AT_R 4
#define AT_TN 64
#define AT_NT (BN / AT_TN)

__global__ __launch_bounds__(256, 2) void attn_kernel(
    const float* __restrict__ Q, const float* __restrict__ K0,
    const float* __restrict__ V0, const float* __restrict__ ekp,
    const float* __restrict__ evp, const int* __restrict__ adj,
    const int* __restrict__ ety, float* __restrict__ O) {
  __shared__ float ks[AT_TN][132];          // K tile, 128 cols + 4 pad
  __shared__ float e_s[AT_R][4][AT_TN];     // unnormalized attn weights
  __shared__ float q_s[AT_R][128];          // q rows for this head group
  __shared__ int tg_s[AT_R][AT_TN];         // 0/1 = edge type, 2 = masked
  __shared__ float qe_s[AT_R][4][2];        // pre-scaled q.ek
  __shared__ float den_s[AT_R][4];
  __shared__ float s1_s[AT_R][4];

  const int tid = threadIdx.x;
  const int hg = blockIdx.y;             // 0..1, heads hg*4 .. hg*4+3
  const int row0 = blockIdx.x * AT_R;
  const int h = tid >> 6;                // local head (wave index)
  const int n_sub = tid & 63;            // A-phase n within tile
  const int d4 = (tid >> 3) & 7;         // B-phase d-chunk
  const int n_oct = tid & 7;             // B-phase n-octet
  const float scale = 0.17677669529663687f;  // 1/sqrt(32)

  // ---- stage q ----
  if (tid < 128) {
    int r = tid >> 5, c4 = tid & 31;
    *(float4*)&q_s[r][c4 * 4] =
        *(const float4*)(Q + (size_t)(row0 + r) * D + hg * 128 + c4 * 4);
  }
  __syncthreads();
  // ---- qe[r][h][t] = scale * q . ek_head ----
  if (tid < 32) {
    int r = tid >> 3, hh = (tid >> 1) & 3, t = tid & 1;
    const float* ep = ekp + t * D + (hg * 4 + hh) * DH;
    float s = 0.f;
#pragma unroll
    for (int i = 0; i < 8; ++i) {
      float4 a = *(const float4*)&q_s[r][hh * 32 + i * 4];
      float4 b = *(const float4*)(ep + i * 4);
      s += a.x * b.x + a.y * b.y + a.z * b.z + a.w * b.w;
    }
    qe_s[r][hh][t] = s * scale;
  }

  float den_loc[AT_R] = {0.f, 0.f, 0.f, 0.f};
  float s1_loc[AT_R] = {0.f, 0.f, 0.f, 0.f};
  float4 acc[AT_R] = {{0,0,0,0},{0,0,0,0},{0,0,0,0},{0,0,0,0}};

  for (int tile = 0; tile < AT_NT; ++tile) {
    const int n0 = tile * AT_TN;
    // ---- stage K-tile (coalesced) ----
#pragma unroll
    for (int j = 0; j < 8; ++j) {
      int idx = j * 256 + tid;
      int rr = idx >> 5, c4 = idx & 31;
      float4 k4 = *(const float4*)(K0 + (size_t)(n0 + rr) * D + hg * 128 + c4 * 4);
      *(float4*)&ks[rr][c4 * 4] = k4;
    }
    // ---- stage tags ----
    {
      int r = tid >> 6, n = tid & 63;
      int a = adj[(size_t)(row0 + r) * BN + n0 + n];
      int t = ety[(size_t)(row0 + r) * BN + n0 + n];
      tg_s[r][n] = a ? t : 2;
    }
    // ---- V tile -> registers (B layout), overlaps with A compute ----
    float4 v4[8];
#pragma unroll
    for (int i = 0; i < 8; ++i) {
      int n = n_oct * 8 + i;
      v4[i] = *(const float4*)(V0 + (size_t)(n0 + n) * D + (hg * 4 + h) * DH + d4 * 4);
    }
    __syncthreads();

    // ---- A: scores/exp ----
    float4 kreg[8];
#pragma unroll
    for (int i = 0; i < 8; ++i) kreg[i] = *(const float4*)&ks[n_sub][h * 32 + i * 4];
#pragma unroll
    for (int r = 0; r < AT_R; ++r) {
      float4 p = {0.f, 0.f, 0.f, 0.f};
#pragma unroll
      for (int i = 0; i < 8; ++i) {
        float4 q4 = *(const float4*)&q_s[r][h * 32 + i * 4];
        p.x = fmaf(q4.x, kreg[i].x, p.x);
        p.y = fmaf(q4.y, kreg[i].y, p.y);
        p.z = fmaf(q4.z, kreg[i].z, p.z);
        p.w = fmaf(q4.w, kreg[i].w, p.w);
      }
      float dot = (p.x + p.y) + (p.z + p.w);
      int tag = tg_s[r][n_sub];
      float qes = qe_s[r][h][tag & 1];
      float e = __expf(fmaf(dot, scale, qes));
      e = (tag == 2) ? 0.f : e;
      e_s[r][h][n_sub] = e;
      den_loc[r] += e;
      s1_loc[r] += (tag == 1) ? e : 0.f;
    }
    __syncthreads();

    // ---- B: accumulate O ----
#pragma unroll
    for (int r = 0; r < AT_R; ++r) {
      float4 e0 = *(const float4*)&e_s[r][h][n_oct * 8];
      float4 e1 = *(const float4*)&e_s[r][h][n_oct * 8 + 4];
      acc[r].x = fmaf(e0.x, v4[0].x, acc[r].x); acc[r].y = fmaf(e0.x, v4[0].y, acc[r].y);
      acc[r].z = fmaf(e0.x, v4[0].z, acc[r].z); acc[r].w = fmaf(e0.x, v4[0].w, acc[r].w);
      acc[r].x = fmaf(e0.y, v4[1].x, acc[r].x); acc[r].y = fmaf(e0.y, v4[1].y, acc[r].y);
      acc[r].z = fmaf(e0.y, v4[1].z, acc[r].z); acc[r].w = fmaf(e0.y, v4[1].w, acc[r].w);
      acc[r].x = fmaf(e0.z, v4[2].x, acc[r].x); acc[r].y = fmaf(e0.z, v4[2].y, acc[r].y);
      acc[r].z = fmaf(e0.z, v4[2].z, acc[r].z); acc[r].w = fmaf(e0.z, v4[2].w, acc[r].w);
      acc[r].x = fmaf(e0.w, v4[3].x, acc[r].x); acc[r].y = fmaf(e0.w, v4[3].y, acc[r].y);
      acc[r].z = fmaf(e0.w, v4[3].z, acc[r].z); acc[r].w = fmaf(e0.w, v4[3].w, acc[r].w);
      acc[r].x = fmaf(e1.x, v4[4].x, acc[r].x); acc[r].y = fmaf(e1.x, v4[4].y, acc[r].y);
      acc[r].z = fmaf(e1.x, v4[4].z, acc[r].z); acc[r].w = fmaf(e1.x, v4[4].w, acc[r].w);
      acc[r].x = fmaf(e1.y, v4[5].x, acc[r].x); acc[r].y = fmaf(e1.y, v4[5].y, acc[r].y);
      acc[r].z = fmaf(e1.y, v4[5].z, acc[r].z); acc[r].w = fmaf(e1.y, v4[5].w, acc[r].w);
      acc[r].x = fmaf(e1.z, v4[6].x, acc[r].x); acc[r].y = fmaf(e1.z, v4[6].y, acc[r].y);
      acc[r].z = fmaf(e1.z, v4[6].z, acc[r].z); acc[r].w = fmaf(e1.z, v4[6].w, acc[r].w);
      acc[r].x = fmaf(e1.w, v4[7].x, acc[r].x); acc[r].y = fmaf(e1.w, v4[7].y, acc[r].y);
      acc[r].z = fmaf(e1.w, v4[7].z, acc[r].z); acc[r].w = fmaf(e1.w, v4[7].w, acc[r].w);
    }
    __syncthreads();
  }

  // ---- reduce denom/s1 across the 64 n_sub lanes of each wave ----
#pragma unroll
  for (int r = 0; r < AT_R; ++r) {
#pragma unroll
    for (int off = 32; off >= 1; off >>= 1) {
      den_loc[r] += __shfl_xor(den_loc[r], off);
      s1_loc[r] += __shfl_xor(s1_loc[r], off);
    }
  }
  if (n_sub == 0) {
#pragma unroll
    for (int r = 0; r < AT_R; ++r) {
      den_s[r][h] = den_loc[r];
      s1_s[r][h] = s1_loc[r];
    }
  }
  __syncthreads();

  // ---- reduce acc across the 8 n_oct lanes, write O ----
#pragma unroll
  for (int r = 0; r < AT_R; ++r) {
#pragma unroll
    for (int off = 1; off <= 4; off <<= 1) {
      acc[r].x += __shfl_xor(acc[r].x, off);
      acc[r].y += __shfl_xor(acc[r].y, off);
      acc[r].z += __shfl_xor(acc[r].z, off);
      acc[r].w += __shfl_xor(acc[r].w, off);
    }
  }
  if (n_oct == 0) {
    const int head = hg * 4 + h;
    const float4 ev0 = *(const float4*)(evp + head * DH + d4 * 4);
    const float4 ev1 = *(const float4*)(evp + D + head * DH + d4 * 4);
#pragma unroll
    for (int r = 0; r < AT_R; ++r) {
      float den = den_s[r][h];
      float s1v = s1_s[r][h];
      float s0v = den - s1v;
      float inv = den > 0.f ? 1.f / den : 0.f;
      float4 o;
      o.x = (acc[r].x + s1v * ev1.x + s0v * ev0.x) * inv;
      o.y = (acc[r].y + s1v * ev1.y + s0v * ev0.y) * inv;
      o.z = (acc[r].z + s1v * ev1.z + s0v * ev0.z) * inv;
      o.w = (acc[r].w + s1v * ev1.w + s0v * ev0.w) * inv;
      *(float4*)&O[(size_t)(row0 + r) * D + head * DH + d4 * 4] = o;
    }
  }
}

// ===========================================================================
extern "C" void kernel_launch(void* const* d_in, const int* in_sizes, int n_in,
                              void* d_out, int out_size, void* d_ws, size_t ws_size,
                              hipStream_t stream) {
  const float* h_target = (const float*)d_in[0];
  const float* h_neigh  = (const float*)d_in[1];
  const int*   adjacency= (const int*)d_in[2];
  const int*   edge_ty  = (const int*)d_in[3];
  const float* Wq = (const float*)d_in[4];
  const float* bq = (const float*)d_in[5];
  const float* Wk = (const float*)d_in[6];
  const float* bk = (const float*)d_in[7];
  const float* Wv = (const float*)d_in[8];
  const float* bv = (const float*)d_in[9];
  const float* Wo = (const float*)d_in[10];
  const float* bo = (const float*)d_in[11];
  const float* E  = (const float*)d_in[12];
  float* out = (float*)d_out;

  float* ws = (float*)d_ws;
  float* Q  = ws;
  float* K0 = Q  + (size_t)BT * D;
  float* V0 = K0 + (size_t)BN * D;
  float* O  = V0 + (size_t)BN * D;
  float* ek = O  + (size_t)BT * D;
  float* ev = ek + 2 * D;

  ekev_kernel<<<dim3(8, 2), 256, 0, stream>>>(E, Wk, Wv, ek, ev);
  qkv_kernel<<<dim3(BT / 4, 3), 256, 0, stream>>>(h_target, h_neigh, Wq, bq, Wk,
                                                  bk, Wv, bv, Q, K0, V0);
  attn_kernel<<<dim3(BT / AT_R, 2), 256, 0, stream>>>(Q, K0, V0, ek, ev,
                                                      adjacency, edge_ty, O);
  proj_out_kernel<<<BT / 4, 256, 0, stream>>>(O, Wo, bo, out);
}

// Round 3
// 121.813 us; speedup vs baseline: 2.1942x; 1.5634x over previous
//
#include <hip/hip_runtime.h>
#include <math.h>

#define BT 1024
#define BN 1024
#define D  256
#define H  8
#define DH 32

typedef __attribute__((ext_vector_type(8))) short short8;
typedef __attribute__((ext_vector_type(4))) float f32x4;

__device__ __forceinline__ unsigned short f2bf(float x) {
  union { float f; unsigned int u; } v; v.f = x;
  unsigned int r = v.u + 0x7fffu + ((v.u >> 16) & 1u);
  return (unsigned short)(r >> 16);
}
__device__ __forceinline__ float bf2f(unsigned short u) {
  union { unsigned int u; float f; } v; v.u = ((unsigned int)u) << 16;
  return v.f;
}

// ===========================================================================
// prep: blocks [0,384) fp32->bf16 conversions; [384,640) tag packing
// (tag = adj ? edge_type : 2, uint8); [640,656) ek/ev = E @ {Wk,Wv}^T (fp32).
// ===========================================================================
__global__ __launch_bounds__(256) void prep_kernel(
    const float* __restrict__ ht, const float* __restrict__ hn,
    const int* __restrict__ adj, const int* __restrict__ ety,
    const float* __restrict__ Wq, const float* __restrict__ Wk,
    const float* __restrict__ Wv, const float* __restrict__ Wo,
    const float* __restrict__ E,
    unsigned char* __restrict__ tags,
    unsigned short* __restrict__ Xtb, unsigned short* __restrict__ Xnb,
    unsigned short* __restrict__ Wqb, unsigned short* __restrict__ Wkb,
    unsigned short* __restrict__ Wvb, unsigned short* __restrict__ Wob,
    float* __restrict__ ek, float* __restrict__ ev) {
  const int blk = blockIdx.x;
  const int tid = threadIdx.x;
  if (blk < 384) {
    const float* src; unsigned short* dst; int base;
    if (blk < 128)      { src = ht; dst = Xtb; base = blk * 2048; }
    else if (blk < 256) { src = hn; dst = Xnb; base = (blk - 128) * 2048; }
    else if (blk < 288) { src = Wq; dst = Wqb; base = (blk - 256) * 2048; }
    else if (blk < 320) { src = Wk; dst = Wkb; base = (blk - 288) * 2048; }
    else if (blk < 352) { src = Wv; dst = Wvb; base = (blk - 320) * 2048; }
    else                { src = Wo; dst = Wob; base = (blk - 352) * 2048; }
    const int e0 = base + tid * 8;
    float4 f0 = *(const float4*)(src + e0);
    float4 f1 = *(const float4*)(src + e0 + 4);
    uint4 o;
    o.x = (unsigned)f2bf(f0.x) | ((unsigned)f2bf(f0.y) << 16);
    o.y = (unsigned)f2bf(f0.z) | ((unsigned)f2bf(f0.w) << 16);
    o.z = (unsigned)f2bf(f1.x) | ((unsigned)f2bf(f1.y) << 16);
    o.w = (unsigned)f2bf(f1.z) | ((unsigned)f2bf(f1.w) << 16);
    *(uint4*)(dst + e0) = o;
  } else if (blk < 640) {
    const int local = blk - 384;
#pragma unroll
    for (int i = 0; i < 4; ++i) {
      int idx = local * 1024 + i * 256 + tid;  // int4 units
      int4 a = ((const int4*)adj)[idx];
      int4 t = ((const int4*)ety)[idx];
      uchar4 o;
      o.x = a.x ? (unsigned char)t.x : (unsigned char)2;
      o.y = a.y ? (unsigned char)t.y : (unsigned char)2;
      o.z = a.z ? (unsigned char)t.z : (unsigned char)2;
      o.w = a.w ? (unsigned char)t.w : (unsigned char)2;
      ((uchar4*)tags)[idx] = o;
    }
  } else {
    const int g = blk - 640;
    const int bx = g & 7, by = g >> 3;
    const int c = tid >> 3, kseg = tid & 7;
    const int col = bx * 32 + c;
    const float* W = by ? Wv : Wk;
    float* outp = by ? ev : ek;
    const float* wrow = W + (size_t)col * D + kseg * 32;
    const float* e0p = E + kseg * 32;
    const float* e1p = E + D + kseg * 32;
    float p0 = 0.f, p1 = 0.f;
#pragma unroll
    for (int i = 0; i < 8; ++i) {
      float4 w4 = *(const float4*)(wrow + i * 4);
      float4 a4 = *(const float4*)(e0p + i * 4);
      float4 b4 = *(const float4*)(e1p + i * 4);
      p0 += w4.x * a4.x + w4.y * a4.y + w4.z * a4.z + w4.w * a4.w;
      p1 += w4.x * b4.x + w4.y * b4.y + w4.z * b4.z + w4.w * b4.w;
    }
#pragma unroll
    for (int off = 1; off <= 4; off <<= 1) {
      p0 += __shfl_xor(p0, off);
      p1 += __shfl_xor(p1, off);
    }
    if (kseg == 0) { outp[col] = p0; outp[D + col] = p1; }
  }
}

// ===========================================================================
// qkv: Y = X @ W^T + b via mfma_f32_16x16x32_bf16. grid (64 M, 4 Ngrp, 3).
// Wave = one 16x16 tile: M-strip = blockIdx.x*16, N = blockIdx.y*64+wid*16.
// A frag: lane reads 16B X[(m0+l16)*256 + k0 + quad*8]; B frag likewise from W.
// Outputs: Q,K as [h][n][32] bf16; V transposed [h][32][n] bf16.
// ===========================================================================
__global__ __launch_bounds__(256) void qkv_mfma(
    const unsigned short* __restrict__ Xtb, const unsigned short* __restrict__ Xnb,
    const unsigned short* __restrict__ Wqb, const unsigned short* __restrict__ Wkb,
    const unsigned short* __restrict__ Wvb,
    const float* __restrict__ bq, const float* __restrict__ bk,
    const float* __restrict__ bv,
    unsigned short* __restrict__ Qh, unsigned short* __restrict__ Kh,
    unsigned short* __restrict__ Vt) {
  const int gm = blockIdx.z;
  const unsigned short* X = (gm == 0) ? Xtb : Xnb;
  const unsigned short* W = (gm == 0) ? Wqb : (gm == 1) ? Wkb : Wvb;
  const float* bias = (gm == 0) ? bq : (gm == 1) ? bk : bv;
  const int lane = threadIdx.x & 63;
  const int wid = threadIdx.x >> 6;
  const int quad = lane >> 4, l16 = lane & 15;
  const int m0 = blockIdx.x * 16;
  const int n0 = blockIdx.y * 64 + wid * 16;
  f32x4 acc = {0.f, 0.f, 0.f, 0.f};
#pragma unroll
  for (int k0 = 0; k0 < 256; k0 += 32) {
    short8 a = *(const short8*)(X + (size_t)(m0 + l16) * 256 + k0 + quad * 8);
    short8 b = *(const short8*)(W + (size_t)(n0 + l16) * 256 + k0 + quad * 8);
    acc = __builtin_amdgcn_mfma_f32_16x16x32_bf16(a, b, acc, 0, 0, 0);
  }
  const int col = n0 + l16;
  const float bia = bias[col];
  const int h = col >> 5, d = col & 31;
  if (gm == 2) {
    // Vt[h][d][m0 + quad*4 + r] ; 4 consecutive neighbors -> one 8B store
    uint2 o;
    o.x = (unsigned)f2bf(acc[0] + bia) | ((unsigned)f2bf(acc[1] + bia) << 16);
    o.y = (unsigned)f2bf(acc[2] + bia) | ((unsigned)f2bf(acc[3] + bia) << 16);
    *(uint2*)(Vt + (size_t)h * 32768 + (size_t)d * 1024 + m0 + quad * 4) = o;
  } else {
    unsigned short* dst = (gm == 0) ? Qh : Kh;
#pragma unroll
    for (int r = 0; r < 4; ++r) {
      int row = m0 + quad * 4 + r;
      dst[(size_t)h * 32768 + (size_t)row * 32 + d] = f2bf(acc[r] + bia);
    }
  }
}

// ===========================================================================
// attn: block = 16 target rows x 1 head, 4 waves. grid (64, 8).
// Per 64-n tile: wave w does QK mfma for n-slice w*16 (K=DH=32 in one mfma),
// exp in C-layout (den/s1 in regs), writes P bf16 to double-buffered LDS,
// one barrier, then PV mfma with wave -> (d-half nt, K-half kc).
// End: shuffle+LDS reduce den/s1, cross-kc acc reduce, ev/den epilogue.
// ===========================================================================
__global__ __launch_bounds__(256) void attn_mfma(
    const unsigned short* __restrict__ Qh, const unsigned short* __restrict__ Kh,
    const unsigned short* __restrict__ Vt,
    const float* __restrict__ ek, const float* __restrict__ ev,
    const unsigned char* __restrict__ tags, unsigned short* __restrict__ Ob) {
  __shared__ unsigned short P[2][16][72];
  __shared__ float qe_s[16][2];
  __shared__ float den_p[4][16];
  __shared__ float s1_p[4][16];
  __shared__ float accb[2][16][17];

  const int h = blockIdx.y;
  const int row0 = blockIdx.x * 16;
  const int tid = threadIdx.x;
  const int wid = tid >> 6;
  const int lane = tid & 63;
  const int quad = lane >> 4, l16 = lane & 15;
  const int nt = wid & 1, kc = wid >> 1;
  const float scale = 0.17677669529663687f;  // 1/sqrt(32)

  const unsigned short* Qbase = Qh + (size_t)h * 32768;
  const unsigned short* Kbase = Kh + (size_t)h * 32768;
  const unsigned short* Vbase = Vt + (size_t)h * 32768;

  short8 aQ = *(const short8*)(Qbase + (size_t)(row0 + l16) * 32 + quad * 8);

  if (tid < 32) {
    int r = tid >> 1, tg = tid & 1;
    const unsigned short* qp = Qbase + (size_t)(row0 + r) * 32;
    const float* ep = ek + tg * D + h * DH;
    float s = 0.f;
#pragma unroll
    for (int dd = 0; dd < 32; ++dd) s += bf2f(qp[dd]) * ep[dd];
    qe_s[r][tg] = s * scale;
  }
  __syncthreads();

  float den_loc[4] = {0.f, 0.f, 0.f, 0.f};
  float s1_loc[4] = {0.f, 0.f, 0.f, 0.f};
  f32x4 acc = {0.f, 0.f, 0.f, 0.f};
  const f32x4 zero = {0.f, 0.f, 0.f, 0.f};

  for (int t = 0; t < 16; ++t) {
    const int n0 = t * 64;
    const int buf = t & 1;
    short8 bK = *(const short8*)(Kbase + (size_t)(n0 + wid * 16 + l16) * 32 + quad * 8);
    f32x4 sc = __builtin_amdgcn_mfma_f32_16x16x32_bf16(aQ, bK, zero, 0, 0, 0);
    const int tn = n0 + wid * 16 + l16;
#pragma unroll
    for (int r = 0; r < 4; ++r) {
      const int row = quad * 4 + r;
      const int tg = tags[(size_t)(row0 + row) * BN + tn];
      float e = 0.f;
      if (tg != 2) e = __expf(fmaf(sc[r], scale, qe_s[row][tg]));
      den_loc[r] += e;
      s1_loc[r] += (tg == 1) ? e : 0.f;
      P[buf][row][wid * 16 + l16] = f2bf(e);
    }
    __syncthreads();
    short8 aP = *(const short8*)&P[buf][l16][kc * 32 + quad * 8];
    short8 bV = *(const short8*)(Vbase + (size_t)(nt * 16 + l16) * 1024 + n0 + kc * 32 + quad * 8);
    acc = __builtin_amdgcn_mfma_f32_16x16x32_bf16(aP, bV, acc, 0, 0, 0);
  }

  // reduce den/s1 across the 16 col-lanes (l16)
#pragma unroll
  for (int r = 0; r < 4; ++r) {
#pragma unroll
    for (int off = 1; off <= 8; off <<= 1) {
      den_loc[r] += __shfl_xor(den_loc[r], off);
      s1_loc[r] += __shfl_xor(s1_loc[r], off);
    }
  }
  if (l16 == 0) {
#pragma unroll
    for (int r = 0; r < 4; ++r) {
      den_p[wid][quad * 4 + r] = den_loc[r];
      s1_p[wid][quad * 4 + r] = s1_loc[r];
    }
  }
  if (kc == 1) {
#pragma unroll
    for (int r = 0; r < 4; ++r) accb[nt][quad * 4 + r][l16] = acc[r];
  }
  __syncthreads();
  if (kc == 0) {
    const int d = nt * 16 + l16;
    const float e0v = ev[h * DH + d];
    const float e1v = ev[D + h * DH + d];
#pragma unroll
    for (int r = 0; r < 4; ++r) {
      const int row = quad * 4 + r;
      float den = den_p[0][row] + den_p[1][row] + den_p[2][row] + den_p[3][row];
      float s1 = s1_p[0][row] + s1_p[1][row] + s1_p[2][row] + s1_p[3][row];
      float s0 = den - s1;
      float inv = den > 0.f ? 1.f / den : 0.f;
      float o = (acc[r] + accb[nt][row][l16] + s1 * e1v + s0 * e0v) * inv;
      Ob[(size_t)(row0 + row) * D + h * DH + d] = f2bf(o);
    }
  }
}

// ===========================================================================
// out = O @ Wo^T + bo (fp32 out). grid (64, 4). Same frag scheme as qkv.
// ===========================================================================
__global__ __launch_bounds__(256) void proj_out_mfma(
    const unsigned short* __restrict__ Ob, const unsigned short* __restrict__ Wob,
    const float* __restrict__ bo, float* __restrict__ out) {
  const int lane = threadIdx.x & 63;
  const int wid = threadIdx.x >> 6;
  const int quad = lane >> 4, l16 = lane & 15;
  const int m0 = blockIdx.x * 16;
  const int n0 = blockIdx.y * 64 + wid * 16;
  f32x4 acc = {0.f, 0.f, 0.f, 0.f};
#pragma unroll
  for (int k0 = 0; k0 < 256; k0 += 32) {
    short8 a = *(const short8*)(Ob + (size_t)(m0 + l16) * 256 + k0 + quad * 8);
    short8 b = *(const short8*)(Wob + (size_t)(n0 + l16) * 256 + k0 + quad * 8);
    acc = __builtin_amdgcn_mfma_f32_16x16x32_bf16(a, b, acc, 0, 0, 0);
  }
  const int col = n0 + l16;
  const float bia = bo[col];
#pragma unroll
  for (int r = 0; r < 4; ++r) {
    out[(size_t)(m0 + quad * 4 + r) * 256 + col] = acc[r] + bia;
  }
}

// ===========================================================================
extern "C" void kernel_launch(void* const* d_in, const int* in_sizes, int n_in,
                              void* d_out, int out_size, void* d_ws, size_t ws_size,
                              hipStream_t stream) {
  const float* h_target = (const float*)d_in[0];
  const float* h_neigh  = (const float*)d_in[1];
  const int*   adjacency= (const int*)d_in[2];
  const int*   edge_ty  = (const int*)d_in[3];
  const float* Wq = (const float*)d_in[4];
  const float* bq = (const float*)d_in[5];
  const float* Wk = (const float*)d_in[6];
  const float* bk = (const float*)d_in[7];
  const float* Wv = (const float*)d_in[8];
  const float* bv = (const float*)d_in[9];
  const float* Wo = (const float*)d_in[10];
  const float* bo = (const float*)d_in[11];
  const float* E  = (const float*)d_in[12];
  float* out = (float*)d_out;

  unsigned char* wsb = (unsigned char*)d_ws;
  unsigned char*  tags = wsb;                                  // 1 MB
  unsigned short* Qh  = (unsigned short*)(wsb + 0x100000);     // 512 KB
  unsigned short* Kh  = (unsigned short*)(wsb + 0x180000);     // 512 KB
  unsigned short* Vt  = (unsigned short*)(wsb + 0x200000);     // 512 KB
  unsigned short* Ob  = (unsigned short*)(wsb + 0x280000);     // 512 KB
  unsigned short* Xtb = (unsigned short*)(wsb + 0x300000);     // 512 KB
  unsigned short* Xnb = (unsigned short*)(wsb + 0x380000);     // 512 KB
  unsigned short* Wqb = (unsigned short*)(wsb + 0x400000);     // 128 KB
  unsigned short* Wkb = (unsigned short*)(wsb + 0x420000);
  unsigned short* Wvb = (unsigned short*)(wsb + 0x440000);
  unsigned short* Wob = (unsigned short*)(wsb + 0x460000);
  float* ek = (float*)(wsb + 0x480000);                        // 2 KB
  float* ev = (float*)(wsb + 0x480800);                        // 2 KB

  prep_kernel<<<656, 256, 0, stream>>>(h_target, h_neigh, adjacency, edge_ty,
                                       Wq, Wk, Wv, Wo, E, tags, Xtb, Xnb,
                                       Wqb, Wkb, Wvb, Wob, ek, ev);
  qkv_mfma<<<dim3(64, 4, 3), 256, 0, stream>>>(Xtb, Xnb, Wqb, Wkb, Wvb,
                                               bq, bk, bv, Qh, Kh, Vt);
  attn_mfma<<<dim3(64, 8), 256, 0, stream>>>(Qh, Kh, Vt, ek, ev, tags, Ob);
  proj_out_mfma<<<dim3(64, 4), 256, 0, stream>>>(Ob, Wob, bo, out);
}

// Round 4
// 114.330 us; speedup vs baseline: 2.3378x; 1.0654x over previous
//
#include <hip/hip_runtime.h>
#include <math.h>

#define BT 1024
#define BN 1024
#define D  256
#define H  8
#define DH 32

typedef __attribute__((ext_vector_type(8))) short short8;
typedef __attribute__((ext_vector_type(4))) float f32x4;

__device__ __forceinline__ unsigned short f2bf(float x) {
  union { float f; unsigned int u; } v; v.f = x;
  unsigned int r = v.u + 0x7fffu + ((v.u >> 16) & 1u);
  return (unsigned short)(r >> 16);
}
__device__ __forceinline__ float bf2f(unsigned short u) {
  union { unsigned int u; float f; } v; v.u = ((unsigned int)u) << 16;
  return v.f;
}
__device__ __forceinline__ unsigned pack2(float a, float b) {
  return (unsigned)f2bf(a) | ((unsigned)f2bf(b) << 16);
}

// ===========================================================================
// prep: blocks [0,256): tag transpose -> tagsT[n][row] = adj ? et : 2 (u8).
//       blocks [256,272): ek/ev = E @ {Wk,Wv}^T (fp32, no bias).
// ===========================================================================
__global__ __launch_bounds__(256) void prep_kernel(
    const int* __restrict__ adj, const int* __restrict__ ety,
    const float* __restrict__ Wk, const float* __restrict__ Wv,
    const float* __restrict__ E, unsigned char* __restrict__ tagsT,
    float* __restrict__ ek, float* __restrict__ ev) {
  const int blk = blockIdx.x;
  const int tid = threadIdx.x;
  if (blk < 256) {
    __shared__ unsigned char tl[64][68];
    const int row0 = (blk >> 4) * 64;
    const int n0 = (blk & 15) * 64;
#pragma unroll
    for (int j = 0; j < 4; ++j) {
      int row = j * 16 + (tid >> 4);
      int c0 = (tid & 15) * 4;
      int4 a = *(const int4*)(adj + (size_t)(row0 + row) * BN + n0 + c0);
      int4 t = *(const int4*)(ety + (size_t)(row0 + row) * BN + n0 + c0);
      tl[c0 + 0][row] = a.x ? (unsigned char)t.x : (unsigned char)2;
      tl[c0 + 1][row] = a.y ? (unsigned char)t.y : (unsigned char)2;
      tl[c0 + 2][row] = a.z ? (unsigned char)t.z : (unsigned char)2;
      tl[c0 + 3][row] = a.w ? (unsigned char)t.w : (unsigned char)2;
    }
    __syncthreads();
#pragma unroll
    for (int j = 0; j < 4; ++j) {
      int idx = j * 256 + tid;
      int nl = idx >> 4, rs = idx & 15;
      uchar4 v = *(const uchar4*)&tl[nl][rs * 4];
      *(uchar4*)(tagsT + (size_t)(n0 + nl) * BT + row0 + rs * 4) = v;
    }
  } else {
    const int g = blk - 256;
    const int bx = g & 7, by = g >> 3;
    const int c = tid >> 3, kseg = tid & 7;
    const int col = bx * 32 + c;
    const float* W = by ? Wv : Wk;
    float* outp = by ? ev : ek;
    const float* wrow = W + (size_t)col * D + kseg * 32;
    const float* e0p = E + kseg * 32;
    const float* e1p = E + D + kseg * 32;
    float p0 = 0.f, p1 = 0.f;
#pragma unroll
    for (int i = 0; i < 8; ++i) {
      float4 w4 = *(const float4*)(wrow + i * 4);
      float4 a4 = *(const float4*)(e0p + i * 4);
      float4 b4 = *(const float4*)(e1p + i * 4);
      p0 += w4.x * a4.x + w4.y * a4.y + w4.z * a4.z + w4.w * a4.w;
      p1 += w4.x * b4.x + w4.y * b4.y + w4.z * b4.z + w4.w * b4.w;
    }
#pragma unroll
    for (int off = 1; off <= 4; off <<= 1) {
      p0 += __shfl_xor(p0, off);
      p1 += __shfl_xor(p1, off);
    }
    if (kseg == 0) { outp[col] = p0; outp[D + col] = p1; }
  }
}

// ===========================================================================
// qkv: Y = X @ W^T + b via MFMA, fp32 inputs converted to bf16 during LDS
// staging (no separate conversion pass). grid (64 M, 4 Ngrp, 3 mats).
// Block: M-strip 16 x N-group 64, K=256. Wave w -> 16x16 tile at n off w*16.
// Outputs: Q,K as [h][n][32] bf16; V transposed [h][32][n] bf16.
// ===========================================================================
__global__ __launch_bounds__(256) void qkv_mfma(
    const float* __restrict__ ht, const float* __restrict__ hn,
    const float* __restrict__ Wq, const float* __restrict__ bq,
    const float* __restrict__ Wk, const float* __restrict__ bk,
    const float* __restrict__ Wv, const float* __restrict__ bv,
    unsigned short* __restrict__ Qh, unsigned short* __restrict__ Kh,
    unsigned short* __restrict__ Vt) {
  const int gm = blockIdx.z;
  const float* X = (gm == 0) ? ht : hn;
  const float* W = (gm == 0) ? Wq : (gm == 1) ? Wk : Wv;
  const float* bias = (gm == 0) ? bq : (gm == 1) ? bk : bv;

  __shared__ unsigned short als[16][264];
  __shared__ unsigned short bls[64][264];

  const int tid = threadIdx.x;
  const int m0 = blockIdx.x * 16;
  const int nb0 = blockIdx.y * 64;
  const int c = (tid & 15) * 16;
  {
    // stage A: 16 rows x 256 cols fp32 -> bf16
    int row = tid >> 4;
    const float* s = X + (size_t)(m0 + row) * D + c;
    uint4 u0, u1;
    float4 f;
    f = *(const float4*)(s + 0);  u0.x = pack2(f.x, f.y); u0.y = pack2(f.z, f.w);
    f = *(const float4*)(s + 4);  u0.z = pack2(f.x, f.y); u0.w = pack2(f.z, f.w);
    f = *(const float4*)(s + 8);  u1.x = pack2(f.x, f.y); u1.y = pack2(f.z, f.w);
    f = *(const float4*)(s + 12); u1.z = pack2(f.x, f.y); u1.w = pack2(f.z, f.w);
    *(uint4*)&als[row][c] = u0;
    *(uint4*)&als[row][c + 8] = u1;
  }
#pragma unroll
  for (int j = 0; j < 4; ++j) {
    // stage B: 64 rows x 256 cols
    int row = j * 16 + (tid >> 4);
    const float* s = W + (size_t)(nb0 + row) * D + c;
    uint4 u0, u1;
    float4 f;
    f = *(const float4*)(s + 0);  u0.x = pack2(f.x, f.y); u0.y = pack2(f.z, f.w);
    f = *(const float4*)(s + 4);  u0.z = pack2(f.x, f.y); u0.w = pack2(f.z, f.w);
    f = *(const float4*)(s + 8);  u1.x = pack2(f.x, f.y); u1.y = pack2(f.z, f.w);
    f = *(const float4*)(s + 12); u1.z = pack2(f.x, f.y); u1.w = pack2(f.z, f.w);
    *(uint4*)&bls[row][c] = u0;
    *(uint4*)&bls[row][c + 8] = u1;
  }
  __syncthreads();

  const int lane = tid & 63, wid = tid >> 6;
  const int quad = lane >> 4, l16 = lane & 15;
  f32x4 acc0 = {0.f, 0.f, 0.f, 0.f};
  f32x4 acc1 = {0.f, 0.f, 0.f, 0.f};
#pragma unroll
  for (int k0 = 0; k0 < 128; k0 += 32) {
    short8 a = *(const short8*)&als[l16][k0 + quad * 8];
    short8 b = *(const short8*)&bls[wid * 16 + l16][k0 + quad * 8];
    acc0 = __builtin_amdgcn_mfma_f32_16x16x32_bf16(a, b, acc0, 0, 0, 0);
  }
#pragma unroll
  for (int k0 = 128; k0 < 256; k0 += 32) {
    short8 a = *(const short8*)&als[l16][k0 + quad * 8];
    short8 b = *(const short8*)&bls[wid * 16 + l16][k0 + quad * 8];
    acc1 = __builtin_amdgcn_mfma_f32_16x16x32_bf16(a, b, acc1, 0, 0, 0);
  }
  f32x4 acc = acc0 + acc1;

  const int col = nb0 + wid * 16 + l16;
  const float bia = bias[col];
  const int h = col >> 5, d = col & 31;
  if (gm == 2) {
    uint2 o;
    o.x = pack2(acc[0] + bia, acc[1] + bia);
    o.y = pack2(acc[2] + bia, acc[3] + bia);
    *(uint2*)(Vt + (size_t)h * 32768 + (size_t)d * 1024 + m0 + quad * 4) = o;
  } else {
    unsigned short* dst = (gm == 0) ? Qh : Kh;
#pragma unroll
    for (int r = 0; r < 4; ++r) {
      int row = m0 + quad * 4 + r;
      dst[(size_t)h * 32768 + (size_t)row * 32 + d] = f2bf(acc[r] + bia);
    }
  }
}

// ===========================================================================
// attn: block = 16 rows x 1 head, 4 waves, n-tiles of 128 (8 barriers).
// Per tile: 2 QK MFMAs/wave -> exp (tags via one uchar4 load per slice)
// -> P bf16 (double-buffered LDS) -> barrier -> 2 PV MFMAs/wave.
// ===========================================================================
__global__ __launch_bounds__(256) void attn_mfma(
    const unsigned short* __restrict__ Qh, const unsigned short* __restrict__ Kh,
    const unsigned short* __restrict__ Vt,
    const float* __restrict__ ek, const float* __restrict__ ev,
    const unsigned char* __restrict__ tagsT, unsigned short* __restrict__ Ob) {
  __shared__ unsigned short P[2][16][136];  // 128 cols + 8 pad
  __shared__ float qe_s[16][2];
  __shared__ float den_p[4][16];
  __shared__ float s1_p[4][16];
  __shared__ float accb[2][16][17];

  const int h = blockIdx.y;
  const int row0 = blockIdx.x * 16;
  const int tid = threadIdx.x;
  const int wid = tid >> 6;
  const int lane = tid & 63;
  const int quad = lane >> 4, l16 = lane & 15;
  const int nt = wid & 1, kc = wid >> 1;
  const float scale = 0.17677669529663687f;  // 1/sqrt(32)

  const unsigned short* Qbase = Qh + (size_t)h * 32768;
  const unsigned short* Kbase = Kh + (size_t)h * 32768;
  const unsigned short* Vbase = Vt + (size_t)h * 32768;

  short8 aQ = *(const short8*)(Qbase + (size_t)(row0 + l16) * 32 + quad * 8);

  if (tid < 32) {
    int r = tid >> 1, tg = tid & 1;
    const unsigned short* qp = Qbase + (size_t)(row0 + r) * 32;
    const float* ep = ek + tg * D + h * DH;
    float s = 0.f;
#pragma unroll
    for (int dd = 0; dd < 32; ++dd) s += bf2f(qp[dd]) * ep[dd];
    qe_s[r][tg] = s * scale;
  }
  __syncthreads();

  float den_loc[4] = {0.f, 0.f, 0.f, 0.f};
  float s1_loc[4] = {0.f, 0.f, 0.f, 0.f};
  f32x4 acc0 = {0.f, 0.f, 0.f, 0.f};
  f32x4 acc1 = {0.f, 0.f, 0.f, 0.f};
  const f32x4 zero = {0.f, 0.f, 0.f, 0.f};

  for (int t = 0; t < 8; ++t) {
    const int n0 = t * 128;
    const int buf = t & 1;
#pragma unroll
    for (int s = 0; s < 2; ++s) {
      const int nc = s * 64 + wid * 16;  // col offset within tile
      short8 bK = *(const short8*)(Kbase + (size_t)(n0 + nc + l16) * 32 + quad * 8);
      f32x4 sc = __builtin_amdgcn_mfma_f32_16x16x32_bf16(aQ, bK, zero, 0, 0, 0);
      const int tn = n0 + nc + l16;
      uchar4 tg4 = *(const uchar4*)(tagsT + (size_t)tn * BT + row0 + quad * 4);
      const unsigned char tga[4] = {tg4.x, tg4.y, tg4.z, tg4.w};
#pragma unroll
      for (int r = 0; r < 4; ++r) {
        const int row = quad * 4 + r;
        const int tg = tga[r];
        float e = 0.f;
        if (tg != 2) e = __expf(fmaf(sc[r], scale, qe_s[row][tg]));
        den_loc[r] += e;
        s1_loc[r] += (tg == 1) ? e : 0.f;
        P[buf][row][nc + l16] = f2bf(e);
      }
    }
    __syncthreads();
    short8 aP0 = *(const short8*)&P[buf][l16][kc * 64 + quad * 8];
    short8 aP1 = *(const short8*)&P[buf][l16][kc * 64 + 32 + quad * 8];
    short8 bV0 = *(const short8*)(Vbase + (size_t)(nt * 16 + l16) * 1024 + n0 + kc * 64 + quad * 8);
    short8 bV1 = *(const short8*)(Vbase + (size_t)(nt * 16 + l16) * 1024 + n0 + kc * 64 + 32 + quad * 8);
    acc0 = __builtin_amdgcn_mfma_f32_16x16x32_bf16(aP0, bV0, acc0, 0, 0, 0);
    acc1 = __builtin_amdgcn_mfma_f32_16x16x32_bf16(aP1, bV1, acc1, 0, 0, 0);
  }
  f32x4 acc = acc0 + acc1;

  // reduce den/s1 across the 16 col-lanes (l16)
#pragma unroll
  for (int r = 0; r < 4; ++r) {
#pragma unroll
    for (int off = 1; off <= 8; off <<= 1) {
      den_loc[r] += __shfl_xor(den_loc[r], off);
      s1_loc[r] += __shfl_xor(s1_loc[r], off);
    }
  }
  if (l16 == 0) {
#pragma unroll
    for (int r = 0; r < 4; ++r) {
      den_p[wid][quad * 4 + r] = den_loc[r];
      s1_p[wid][quad * 4 + r] = s1_loc[r];
    }
  }
  if (kc == 1) {
#pragma unroll
    for (int r = 0; r < 4; ++r) accb[nt][quad * 4 + r][l16] = acc[r];
  }
  __syncthreads();
  if (kc == 0) {
    const int d = nt * 16 + l16;
    const float e0v = ev[h * DH + d];
    const float e1v = ev[D + h * DH + d];
#pragma unroll
    for (int r = 0; r < 4; ++r) {
      const int row = quad * 4 + r;
      float den = den_p[0][row] + den_p[1][row] + den_p[2][row] + den_p[3][row];
      float s1 = s1_p[0][row] + s1_p[1][row] + s1_p[2][row] + s1_p[3][row];
      float s0 = den - s1;
      float inv = den > 0.f ? 1.f / den : 0.f;
      float o = (acc[r] + accb[nt][row][l16] + s1 * e1v + s0 * e0v) * inv;
      Ob[(size_t)(row0 + row) * D + h * DH + d] = f2bf(o);
    }
  }
}

// ===========================================================================
// out = O @ Wo^T + bo (fp32 out). Wo staged fp32->bf16 via LDS. grid (64,4).
// ===========================================================================
__global__ __launch_bounds__(256) void proj_out_mfma(
    const unsigned short* __restrict__ Ob, const float* __restrict__ Wo,
    const float* __restrict__ bo, float* __restrict__ out) {
  __shared__ unsigned short bls[64][264];
  const int tid = threadIdx.x;
  const int m0 = blockIdx.x * 16;
  const int nb0 = blockIdx.y * 64;
  const int c = (tid & 15) * 16;
#pragma unroll
  for (int j = 0; j < 4; ++j) {
    int row = j * 16 + (tid >> 4);
    const float* s = Wo + (size_t)(nb0 + row) * D + c;
    uint4 u0, u1;
    float4 f;
    f = *(const float4*)(s + 0);  u0.x = pack2(f.x, f.y); u0.y = pack2(f.z, f.w);
    f = *(const float4*)(s + 4);  u0.z = pack2(f.x, f.y); u0.w = pack2(f.z, f.w);
    f = *(const float4*)(s + 8);  u1.x = pack2(f.x, f.y); u1.y = pack2(f.z, f.w);
    f = *(const float4*)(s + 12); u1.z = pack2(f.x, f.y); u1.w = pack2(f.z, f.w);
    *(uint4*)&bls[row][c] = u0;
    *(uint4*)&bls[row][c + 8] = u1;
  }
  __syncthreads();

  const int lane = tid & 63, wid = tid >> 6;
  const int quad = lane >> 4, l16 = lane & 15;
  f32x4 acc0 = {0.f, 0.f, 0.f, 0.f};
  f32x4 acc1 = {0.f, 0.f, 0.f, 0.f};
#pragma unroll
  for (int k0 = 0; k0 < 128; k0 += 32) {
    short8 a = *(const short8*)(Ob + (size_t)(m0 + l16) * 256 + k0 + quad * 8);
    short8 b = *(const short8*)&bls[wid * 16 + l16][k0 + quad * 8];
    acc0 = __builtin_amdgcn_mfma_f32_16x16x32_bf16(a, b, acc0, 0, 0, 0);
  }
#pragma unroll
  for (int k0 = 128; k0 < 256; k0 += 32) {
    short8 a = *(const short8*)(Ob + (size_t)(m0 + l16) * 256 + k0 + quad * 8);
    short8 b = *(const short8*)&bls[wid * 16 + l16][k0 + quad * 8];
    acc1 = __builtin_amdgcn_mfma_f32_16x16x32_bf16(a, b, acc1, 0, 0, 0);
  }
  f32x4 acc = acc0 + acc1;
  const int col = nb0 + wid * 16 + l16;
  const float bia = bo[col];
#pragma unroll
  for (int r = 0; r < 4; ++r) {
    out[(size_t)(m0 + quad * 4 + r) * 256 + col] = acc[r] + bia;
  }
}

// ===========================================================================
extern "C" void kernel_launch(void* const* d_in, const int* in_sizes, int n_in,
                              void* d_out, int out_size, void* d_ws, size_t ws_size,
                              hipStream_t stream) {
  const float* h_target = (const float*)d_in[0];
  const float* h_neigh  = (const float*)d_in[1];
  const int*   adjacency= (const int*)d_in[2];
  const int*   edge_ty  = (const int*)d_in[3];
  const float* Wq = (const float*)d_in[4];
  const float* bq = (const float*)d_in[5];
  const float* Wk = (const float*)d_in[6];
  const float* bk = (const float*)d_in[7];
  const float* Wv = (const float*)d_in[8];
  const float* bv = (const float*)d_in[9];
  const float* Wo = (const float*)d_in[10];
  const float* bo = (const float*)d_in[11];
  const float* E  = (const float*)d_in[12];
  float* out = (float*)d_out;

  unsigned char* wsb = (unsigned char*)d_ws;
  unsigned char*  tagsT = wsb;                                 // 1 MB
  unsigned short* Qh = (unsigned short*)(wsb + 0x100000);      // 512 KB
  unsigned short* Kh = (unsigned short*)(wsb + 0x180000);      // 512 KB
  unsigned short* Vt = (unsigned short*)(wsb + 0x200000);      // 512 KB
  unsigned short* Ob = (unsigned short*)(wsb + 0x280000);      // 512 KB
  float* ek = (float*)(wsb + 0x300000);                        // 2 KB
  float* ev = (float*)(wsb + 0x300800);                        // 2 KB

  prep_kernel<<<272, 256, 0, stream>>>(adjacency, edge_ty, Wk, Wv, E,
                                       tagsT, ek, ev);
  qkv_mfma<<<dim3(64, 4, 3), 256, 0, stream>>>(h_target, h_neigh, Wq, bq, Wk,
                                               bk, Wv, bv, Qh, Kh, Vt);
  attn_mfma<<<dim3(64, 8), 256, 0, stream>>>(Qh, Kh, Vt, ek, ev, tagsT, Ob);
  proj_out_mfma<<<dim3(64, 4), 256, 0, stream>>>(Ob, Wo, bo, out);
}

// Round 5
// 110.369 us; speedup vs baseline: 2.4217x; 1.0359x over previous
//
#include <hip/hip_runtime.h>
#include <math.h>

#define BT 1024
#define BN 1024
#define D  256
#define H  8
#define DH 32

typedef __attribute__((ext_vector_type(8))) short short8;
typedef __attribute__((ext_vector_type(4))) float f32x4;

__device__ __forceinline__ unsigned short f2bf(float x) {
  union { float f; unsigned int u; } v; v.f = x;
  unsigned int r = v.u + 0x7fffu + ((v.u >> 16) & 1u);
  return (unsigned short)(r >> 16);
}
__device__ __forceinline__ float bf2f(unsigned short u) {
  union { unsigned int u; float f; } v; v.u = ((unsigned int)u) << 16;
  return v.f;
}
__device__ __forceinline__ unsigned pack2(float a, float b) {
  return (unsigned)f2bf(a) | ((unsigned)f2bf(b) << 16);
}

// ===========================================================================
// Dispatch 1 (fused): blocks [0,768)   qkv GEMMs (Q/K0/V0, fp32->bf16 in LDS)
//                     blocks [768,1024) tag transpose tagsT[n][row]
//                     blocks [1024,1040) ek/ev = E @ {Wk,Wv}^T
//                     blocks [1040,1056) Wo fp32 -> bf16 (Wob)
// ===========================================================================
__global__ __launch_bounds__(256) void fused_prep_qkv(
    const float* __restrict__ ht, const float* __restrict__ hn,
    const int* __restrict__ adj, const int* __restrict__ ety,
    const float* __restrict__ Wq, const float* __restrict__ bq,
    const float* __restrict__ Wk, const float* __restrict__ bk,
    const float* __restrict__ Wv, const float* __restrict__ bv,
    const float* __restrict__ Wo, const float* __restrict__ E,
    unsigned char* __restrict__ tagsT, float* __restrict__ ek,
    float* __restrict__ ev, unsigned short* __restrict__ Qh,
    unsigned short* __restrict__ Kh, unsigned short* __restrict__ Vt,
    unsigned short* __restrict__ Wob) {
  const int blk = blockIdx.x;
  const int tid = threadIdx.x;

  if (blk < 768) {
    // ---------------- qkv GEMM ----------------
    const int gm = blk >> 8;           // 0=Q, 1=K, 2=V
    const int rem = blk & 255;
    const int m0 = (rem & 63) * 16;    // M strip
    const int nb0 = (rem >> 6) * 64;   // N group
    const float* X = (gm == 0) ? ht : hn;
    const float* W = (gm == 0) ? Wq : (gm == 1) ? Wk : Wv;
    const float* bias = (gm == 0) ? bq : (gm == 1) ? bk : bv;

    __shared__ unsigned short als[16][264];
    __shared__ unsigned short bls[64][264];

    const int c = (tid & 15) * 16;
    {
      int row = tid >> 4;
      const float* s = X + (size_t)(m0 + row) * D + c;
      uint4 u0, u1;
      float4 f;
      f = *(const float4*)(s + 0);  u0.x = pack2(f.x, f.y); u0.y = pack2(f.z, f.w);
      f = *(const float4*)(s + 4);  u0.z = pack2(f.x, f.y); u0.w = pack2(f.z, f.w);
      f = *(const float4*)(s + 8);  u1.x = pack2(f.x, f.y); u1.y = pack2(f.z, f.w);
      f = *(const float4*)(s + 12); u1.z = pack2(f.x, f.y); u1.w = pack2(f.z, f.w);
      *(uint4*)&als[row][c] = u0;
      *(uint4*)&als[row][c + 8] = u1;
    }
#pragma unroll
    for (int j = 0; j < 4; ++j) {
      int row = j * 16 + (tid >> 4);
      const float* s = W + (size_t)(nb0 + row) * D + c;
      uint4 u0, u1;
      float4 f;
      f = *(const float4*)(s + 0);  u0.x = pack2(f.x, f.y); u0.y = pack2(f.z, f.w);
      f = *(const float4*)(s + 4);  u0.z = pack2(f.x, f.y); u0.w = pack2(f.z, f.w);
      f = *(const float4*)(s + 8);  u1.x = pack2(f.x, f.y); u1.y = pack2(f.z, f.w);
      f = *(const float4*)(s + 12); u1.z = pack2(f.x, f.y); u1.w = pack2(f.z, f.w);
      *(uint4*)&bls[row][c] = u0;
      *(uint4*)&bls[row][c + 8] = u1;
    }
    __syncthreads();

    const int lane = tid & 63, wid = tid >> 6;
    const int quad = lane >> 4, l16 = lane & 15;
    f32x4 acc0 = {0.f, 0.f, 0.f, 0.f};
    f32x4 acc1 = {0.f, 0.f, 0.f, 0.f};
#pragma unroll
    for (int k0 = 0; k0 < 128; k0 += 32) {
      short8 a = *(const short8*)&als[l16][k0 + quad * 8];
      short8 b = *(const short8*)&bls[wid * 16 + l16][k0 + quad * 8];
      acc0 = __builtin_amdgcn_mfma_f32_16x16x32_bf16(a, b, acc0, 0, 0, 0);
    }
#pragma unroll
    for (int k0 = 128; k0 < 256; k0 += 32) {
      short8 a = *(const short8*)&als[l16][k0 + quad * 8];
      short8 b = *(const short8*)&bls[wid * 16 + l16][k0 + quad * 8];
      acc1 = __builtin_amdgcn_mfma_f32_16x16x32_bf16(a, b, acc1, 0, 0, 0);
    }
    f32x4 acc = acc0 + acc1;

    const int col = nb0 + wid * 16 + l16;
    const float bia = bias[col];
    const int h = col >> 5, d = col & 31;
    if (gm == 2) {
      uint2 o;
      o.x = pack2(acc[0] + bia, acc[1] + bia);
      o.y = pack2(acc[2] + bia, acc[3] + bia);
      *(uint2*)(Vt + (size_t)h * 32768 + (size_t)d * 1024 + m0 + quad * 4) = o;
    } else {
      unsigned short* dst = (gm == 0) ? Qh : Kh;
#pragma unroll
      for (int r = 0; r < 4; ++r) {
        int row = m0 + quad * 4 + r;
        dst[(size_t)h * 32768 + (size_t)row * 32 + d] = f2bf(acc[r] + bia);
      }
    }
  } else if (blk < 1024) {
    // ---------------- tag transpose ----------------
    const int local = blk - 768;
    __shared__ unsigned char tl[64][68];
    const int row0 = (local >> 4) * 64;
    const int n0 = (local & 15) * 64;
#pragma unroll
    for (int j = 0; j < 4; ++j) {
      int row = j * 16 + (tid >> 4);
      int c0 = (tid & 15) * 4;
      int4 a = *(const int4*)(adj + (size_t)(row0 + row) * BN + n0 + c0);
      int4 t = *(const int4*)(ety + (size_t)(row0 + row) * BN + n0 + c0);
      tl[c0 + 0][row] = a.x ? (unsigned char)t.x : (unsigned char)2;
      tl[c0 + 1][row] = a.y ? (unsigned char)t.y : (unsigned char)2;
      tl[c0 + 2][row] = a.z ? (unsigned char)t.z : (unsigned char)2;
      tl[c0 + 3][row] = a.w ? (unsigned char)t.w : (unsigned char)2;
    }
    __syncthreads();
#pragma unroll
    for (int j = 0; j < 4; ++j) {
      int idx = j * 256 + tid;
      int nl = idx >> 4, rs = idx & 15;
      uchar4 v = *(const uchar4*)&tl[nl][rs * 4];
      *(uchar4*)(tagsT + (size_t)(n0 + nl) * BT + row0 + rs * 4) = v;
    }
  } else if (blk < 1040) {
    // ---------------- ek/ev ----------------
    const int g = blk - 1024;
    const int bx = g & 7, by = g >> 3;
    const int c = tid >> 3, kseg = tid & 7;
    const int col = bx * 32 + c;
    const float* W = by ? Wv : Wk;
    float* outp = by ? ev : ek;
    const float* wrow = W + (size_t)col * D + kseg * 32;
    const float* e0p = E + kseg * 32;
    const float* e1p = E + D + kseg * 32;
    float p0 = 0.f, p1 = 0.f;
#pragma unroll
    for (int i = 0; i < 8; ++i) {
      float4 w4 = *(const float4*)(wrow + i * 4);
      float4 a4 = *(const float4*)(e0p + i * 4);
      float4 b4 = *(const float4*)(e1p + i * 4);
      p0 += w4.x * a4.x + w4.y * a4.y + w4.z * a4.z + w4.w * a4.w;
      p1 += w4.x * b4.x + w4.y * b4.y + w4.z * b4.z + w4.w * b4.w;
    }
#pragma unroll
    for (int off = 1; off <= 4; off <<= 1) {
      p0 += __shfl_xor(p0, off);
      p1 += __shfl_xor(p1, off);
    }
    if (kseg == 0) { outp[col] = p0; outp[D + col] = p1; }
  } else {
    // ---------------- Wo -> bf16 ----------------
    const int g = blk - 1040;
    const int base = g * 4096;  // shorts
#pragma unroll
    for (int half = 0; half < 2; ++half) {
      int e0 = base + half * 2048 + tid * 8;
      float4 f0 = *(const float4*)(Wo + e0);
      float4 f1 = *(const float4*)(Wo + e0 + 4);
      uint4 o;
      o.x = pack2(f0.x, f0.y);
      o.y = pack2(f0.z, f0.w);
      o.z = pack2(f1.x, f1.y);
      o.w = pack2(f1.z, f1.w);
      *(uint4*)(Wob + e0) = o;
    }
  }
}

// ===========================================================================
// attn: block = 16 rows x 1 head, 4 waves, n-tiles of 128 (8 barriers).
// All VMEM for a tile (bK x2, tags x2, bV x2) issued up front so it overlaps
// exp/pack and the barrier wait. Double-buffered P -> one barrier per tile.
// ===========================================================================
__global__ __launch_bounds__(256) void attn_mfma(
    const unsigned short* __restrict__ Qh, const unsigned short* __restrict__ Kh,
    const unsigned short* __restrict__ Vt,
    const float* __restrict__ ek, const float* __restrict__ ev,
    const unsigned char* __restrict__ tagsT, unsigned short* __restrict__ Ob) {
  __shared__ unsigned short P[2][16][136];
  __shared__ float qe_s[16][2];
  __shared__ float den_p[4][16];
  __shared__ float s1_p[4][16];
  __shared__ float accb[2][16][17];

  const int h = blockIdx.y;
  const int row0 = blockIdx.x * 16;
  const int tid = threadIdx.x;
  const int wid = tid >> 6;
  const int lane = tid & 63;
  const int quad = lane >> 4, l16 = lane & 15;
  const int nt = wid & 1, kc = wid >> 1;
  const float scale = 0.17677669529663687f;  // 1/sqrt(32)

  const unsigned short* Qbase = Qh + (size_t)h * 32768;
  const unsigned short* Kbase = Kh + (size_t)h * 32768;
  const unsigned short* Vbase = Vt + (size_t)h * 32768;

  short8 aQ = *(const short8*)(Qbase + (size_t)(row0 + l16) * 32 + quad * 8);

  if (tid < 32) {
    int r = tid >> 1, tg = tid & 1;
    const unsigned short* qp = Qbase + (size_t)(row0 + r) * 32;
    const float* ep = ek + tg * D + h * DH;
    float s = 0.f;
#pragma unroll
    for (int dd = 0; dd < 32; ++dd) s += bf2f(qp[dd]) * ep[dd];
    qe_s[r][tg] = s * scale;
  }
  __syncthreads();

  float den_loc[4] = {0.f, 0.f, 0.f, 0.f};
  float s1_loc[4] = {0.f, 0.f, 0.f, 0.f};
  f32x4 acc0 = {0.f, 0.f, 0.f, 0.f};
  f32x4 acc1 = {0.f, 0.f, 0.f, 0.f};
  const f32x4 zero = {0.f, 0.f, 0.f, 0.f};

  for (int t = 0; t < 8; ++t) {
    const int n0 = t * 128;
    const int buf = t & 1;
    // ---- issue ALL global loads for this tile up front ----
    const int nc0 = wid * 16;        // s=0 col offset
    const int nc1 = 64 + wid * 16;   // s=1 col offset
    short8 bK0 = *(const short8*)(Kbase + (size_t)(n0 + nc0 + l16) * 32 + quad * 8);
    short8 bK1 = *(const short8*)(Kbase + (size_t)(n0 + nc1 + l16) * 32 + quad * 8);
    uchar4 tg40 = *(const uchar4*)(tagsT + (size_t)(n0 + nc0 + l16) * BT + row0 + quad * 4);
    uchar4 tg41 = *(const uchar4*)(tagsT + (size_t)(n0 + nc1 + l16) * BT + row0 + quad * 4);
    short8 bV0 = *(const short8*)(Vbase + (size_t)(nt * 16 + l16) * 1024 + n0 + kc * 64 + quad * 8);
    short8 bV1 = *(const short8*)(Vbase + (size_t)(nt * 16 + l16) * 1024 + n0 + kc * 64 + 32 + quad * 8);

    f32x4 sc0 = __builtin_amdgcn_mfma_f32_16x16x32_bf16(aQ, bK0, zero, 0, 0, 0);
    f32x4 sc1 = __builtin_amdgcn_mfma_f32_16x16x32_bf16(aQ, bK1, zero, 0, 0, 0);

    const unsigned char tga0[4] = {tg40.x, tg40.y, tg40.z, tg40.w};
    const unsigned char tga1[4] = {tg41.x, tg41.y, tg41.z, tg41.w};
#pragma unroll
    for (int r = 0; r < 4; ++r) {
      const int row = quad * 4 + r;
      const int tg = tga0[r];
      float e = 0.f;
      if (tg != 2) e = __expf(fmaf(sc0[r], scale, qe_s[row][tg]));
      den_loc[r] += e;
      s1_loc[r] += (tg == 1) ? e : 0.f;
      P[buf][row][nc0 + l16] = f2bf(e);
    }
#pragma unroll
    for (int r = 0; r < 4; ++r) {
      const int row = quad * 4 + r;
      const int tg = tga1[r];
      float e = 0.f;
      if (tg != 2) e = __expf(fmaf(sc1[r], scale, qe_s[row][tg]));
      den_loc[r] += e;
      s1_loc[r] += (tg == 1) ? e : 0.f;
      P[buf][row][nc1 + l16] = f2bf(e);
    }
    __syncthreads();
    short8 aP0 = *(const short8*)&P[buf][l16][kc * 64 + quad * 8];
    short8 aP1 = *(const short8*)&P[buf][l16][kc * 64 + 32 + quad * 8];
    acc0 = __builtin_amdgcn_mfma_f32_16x16x32_bf16(aP0, bV0, acc0, 0, 0, 0);
    acc1 = __builtin_amdgcn_mfma_f32_16x16x32_bf16(aP1, bV1, acc1, 0, 0, 0);
  }
  f32x4 acc = acc0 + acc1;

#pragma unroll
  for (int r = 0; r < 4; ++r) {
#pragma unroll
    for (int off = 1; off <= 8; off <<= 1) {
      den_loc[r] += __shfl_xor(den_loc[r], off);
      s1_loc[r] += __shfl_xor(s1_loc[r], off);
    }
  }
  if (l16 == 0) {
#pragma unroll
    for (int r = 0; r < 4; ++r) {
      den_p[wid][quad * 4 + r] = den_loc[r];
      s1_p[wid][quad * 4 + r] = s1_loc[r];
    }
  }
  if (kc == 1) {
#pragma unroll
    for (int r = 0; r < 4; ++r) accb[nt][quad * 4 + r][l16] = acc[r];
  }
  __syncthreads();
  if (kc == 0) {
    const int d = nt * 16 + l16;
    const float e0v = ev[h * DH + d];
    const float e1v = ev[D + h * DH + d];
#pragma unroll
    for (int r = 0; r < 4; ++r) {
      const int row = quad * 4 + r;
      float den = den_p[0][row] + den_p[1][row] + den_p[2][row] + den_p[3][row];
      float s1 = s1_p[0][row] + s1_p[1][row] + s1_p[2][row] + s1_p[3][row];
      float s0 = den - s1;
      float inv = den > 0.f ? 1.f / den : 0.f;
      float o = (acc[r] + accb[nt][row][l16] + s1 * e1v + s0 * e0v) * inv;
      Ob[(size_t)(row0 + row) * D + h * DH + d] = f2bf(o);
    }
  }
}

// ===========================================================================
// out = Ob @ Wob^T + bo (fp32 out). Both fragments direct global 16B loads;
// no LDS, no barriers. grid (64, 4).
// ===========================================================================
__global__ __launch_bounds__(256) void proj_out_mfma(
    const unsigned short* __restrict__ Ob, const unsigned short* __restrict__ Wob,
    const float* __restrict__ bo, float* __restrict__ out) {
  const int lane = threadIdx.x & 63;
  const int wid = threadIdx.x >> 6;
  const int quad = lane >> 4, l16 = lane & 15;
  const int m0 = blockIdx.x * 16;
  const int n0 = blockIdx.y * 64 + wid * 16;
  f32x4 acc0 = {0.f, 0.f, 0.f, 0.f};
  f32x4 acc1 = {0.f, 0.f, 0.f, 0.f};
#pragma unroll
  for (int k0 = 0; k0 < 128; k0 += 32) {
    short8 a = *(const short8*)(Ob + (size_t)(m0 + l16) * 256 + k0 + quad * 8);
    short8 b = *(const short8*)(Wob + (size_t)(n0 + l16) * 256 + k0 + quad * 8);
    acc0 = __builtin_amdgcn_mfma_f32_16x16x32_bf16(a, b, acc0, 0, 0, 0);
  }
#pragma unroll
  for (int k0 = 128; k0 < 256; k0 += 32) {
    short8 a = *(const short8*)(Ob + (size_t)(m0 + l16) * 256 + k0 + quad * 8);
    short8 b = *(const short8*)(Wob + (size_t)(n0 + l16) * 256 + k0 + quad * 8);
    acc1 = __builtin_amdgcn_mfma_f32_16x16x32_bf16(a, b, acc1, 0, 0, 0);
  }
  f32x4 acc = acc0 + acc1;
  const int col = n0 + l16;
  const float bia = bo[col];
#pragma unroll
  for (int r = 0; r < 4; ++r) {
    out[(size_t)(m0 + quad * 4 + r) * 256 + col] = acc[r] + bia;
  }
}

// ===========================================================================
extern "C" void kernel_launch(void* const* d_in, const int* in_sizes, int n_in,
                              void* d_out, int out_size, void* d_ws, size_t ws_size,
                              hipStream_t stream) {
  const float* h_target = (const float*)d_in[0];
  const float* h_neigh  = (const float*)d_in[1];
  const int*   adjacency= (const int*)d_in[2];
  const int*   edge_ty  = (const int*)d_in[3];
  const float* Wq = (const float*)d_in[4];
  const float* bq = (const float*)d_in[5];
  const float* Wk = (const float*)d_in[6];
  const float* bk = (const float*)d_in[7];
  const float* Wv = (const float*)d_in[8];
  const float* bv = (const float*)d_in[9];
  const float* Wo = (const float*)d_in[10];
  const float* bo = (const float*)d_in[11];
  const float* E  = (const float*)d_in[12];
  float* out = (float*)d_out;

  unsigned char* wsb = (unsigned char*)d_ws;
  unsigned char*  tagsT = wsb;                                 // 1 MB
  unsigned short* Qh  = (unsigned short*)(wsb + 0x100000);     // 512 KB
  unsigned short* Kh  = (unsigned short*)(wsb + 0x180000);     // 512 KB
  unsigned short* Vt  = (unsigned short*)(wsb + 0x200000);     // 512 KB
  unsigned short* Ob  = (unsigned short*)(wsb + 0x280000);     // 512 KB
  unsigned short* Wob = (unsigned short*)(wsb + 0x300000);     // 128 KB
  float* ek = (float*)(wsb + 0x320000);                        // 2 KB
  float* ev = (float*)(wsb + 0x320800);                        // 2 KB

  fused_prep_qkv<<<1056, 256, 0, stream>>>(
      h_target, h_neigh, adjacency, edge_ty, Wq, bq, Wk, bk, Wv, bv, Wo, E,
      tagsT, ek, ev, Qh, Kh, Vt, Wob);
  attn_mfma<<<dim3(64, 8), 256, 0, stream>>>(Qh, Kh, Vt, ek, ev, tagsT, Ob);
  proj_out_mfma<<<dim3(64, 4), 256, 0, stream>>>(Ob, Wob, bo, out);
}